// Round 10
// baseline (76.401 us; speedup 1.0000x reference)
//
#include <hip/hip_runtime.h>
#include <hip/hip_bf16.h>

#define BS  32
#define J   4
#define L   512
#define D   768
#define K   4
#define OUT 256
// entity e = b*16 + j*4 + k (reference reshape order); sentence = e>>2 (128)
// 1024 blocks = entity e (512) x half h (2); 256 threads = 4 waves.

typedef float f4 __attribute__((ext_vector_type(4)));

__global__ __launch_bounds__(256, 4) void fused_kernel(
    const float* __restrict__ Z,    // [BS,J,L,D]
    const int*   __restrict__ sep,  // [BS,J,K]
    const float* __restrict__ W,    // [D, OUT]
    const float* __restrict__ bias, // [OUT]
    float*       __restrict__ out,  // [512, OUT]
    float*       __restrict__ ws,   // [512][2][768] scaled half-pools
    int*         __restrict__ cnt)  // [512] arrival counters (zeroed per call)
{
    __shared__ float part[4][D];    // 12 KB: pool cross-wave reduce
    __shared__ float pg[D];         // 3 KB : gemv operand row
    __shared__ f4    red[4][64];    // 4 KB : gemv cross-wave reduce
    __shared__ int   flag;

    const int blk  = blockIdx.x;    // 0..1023
    const int e    = blk >> 1, h = blk & 1;
    const int sent = e >> 2,  k = e & 3;
    const int tid  = threadIdx.x;
    const int w    = tid >> 6;      // wave 0..3
    const int lane = tid & 63;

    // ---------------- Phase A: half-span mean-pool (round-5 proven) ---------
    {
        const int end   = sep[sent * K + k];
        const int prev  = (k == 0) ? 0 : sep[sent * K + k - 1];
        const int start = prev + 1;
        const float inv = 1.0f / (float)(end - start);
        const float* zbase = Z + (size_t)sent * L * D + lane * 4;

        f4 a0={0,0,0,0}, a1={0,0,0,0}, a2={0,0,0,0};
        f4 c0={0,0,0,0}, c1={0,0,0,0}, c2={0,0,0,0};

        int l = start + h + 2 * w;             // this wave: stride 8
        for (; l + 8 < end; l += 16) {         // 2 tokens/iter: 6 loads in flight
            const float* r0 = zbase + (size_t)l * D;
            const float* r1 = zbase + (size_t)(l + 8) * D;
            a0 += *(const f4*)(r0);       a1 += *(const f4*)(r0 + 256);
            a2 += *(const f4*)(r0 + 512);
            c0 += *(const f4*)(r1);       c1 += *(const f4*)(r1 + 256);
            c2 += *(const f4*)(r1 + 512);
        }
        if (l < end) {
            const float* r0 = zbase + (size_t)l * D;
            a0 += *(const f4*)(r0);       a1 += *(const f4*)(r0 + 256);
            a2 += *(const f4*)(r0 + 512);
        }
        a0 += c0; a1 += c1; a2 += c2;

        *(f4*)&part[w][lane*4]       = a0;
        *(f4*)&part[w][lane*4 + 256] = a1;
        *(f4*)&part[w][lane*4 + 512] = a2;
        __syncthreads();

        if (tid < 192) {                       // 192 f4 = 768 floats
            f4 s = {0,0,0,0};
            #pragma unroll
            for (int ww = 0; ww < 4; ++ww) s += *(const f4*)&part[ww][tid*4];
            s *= inv;                          // pre-scale by 1/count
            *(f4*)&ws[((size_t)e * 2 + h) * D + tid*4] = s;
        }
    }
    __syncthreads();   // barrier drains vmcnt: all ws stores of this block issued

    // ---------------- arrival: 2nd half-block to finish does the GEMV -------
    if (tid == 0) {
        // ACQ_REL agent-scope RMW: release flushes our ws writes device-wide,
        // acquire invalidates stale lines before we read the sibling's half.
        flag = __hip_atomic_fetch_add(&cnt[e], 1, __ATOMIC_ACQ_REL,
                                      __HIP_MEMORY_SCOPE_AGENT);
    }
    __syncthreads();
    if (flag != 1) return;                     // first arriver exits

    // ---------------- Phase B: out[e] = (ws[e][0]+ws[e][1]) @ W + bias ------
    {
        const f4* aa = (const f4*)(ws + (size_t)e * 2 * D);
        if (tid < 192) {
            f4 v = aa[tid] + aa[tid + 192];    // halves pre-scaled
            *(f4*)&pg[tid * 4] = v;
        }
    }
    __syncthreads();

    f4 acc = {0,0,0,0};
    const int colb = lane * 4;                 // 64 lanes x f4 = 256 cols
    #pragma unroll 8
    for (int i = 0; i < 192; ++i) {
        const int d = w + 4 * i;               // wave-uniform row index
        f4 wv = *(const f4*)&W[(size_t)d * OUT + colb];  // full 1KB row/wave
        acc += pg[d] * wv;                     // LDS broadcast operand
    }
    red[w][lane] = acc;
    __syncthreads();

    if (tid < 64) {
        f4 o = red[0][tid] + red[1][tid] + red[2][tid] + red[3][tid]
             + *(const f4*)&bias[tid * 4];
        *(f4*)&out[(size_t)e * OUT + tid * 4] = o;       // coalesced 1KB
    }
}

extern "C" void kernel_launch(void* const* d_in, const int* in_sizes, int n_in,
                              void* d_out, int out_size, void* d_ws, size_t ws_size,
                              hipStream_t stream) {
    const float* Z    = (const float*)d_in[0];
    const int*   sep  = (const int*)d_in[1];
    const float* W    = (const float*)d_in[2];
    const float* bias = (const float*)d_in[3];
    float*       out  = (float*)d_out;
    float*       ws   = (float*)d_ws;                  // 3 MB half-pool scratch
    int*         cnt  = (int*)(ws + 512 * 2 * D);      // +2 KB counters

    hipMemsetAsync(cnt, 0, 512 * sizeof(int), stream); // graph-legal memset node
    fused_kernel<<<2 * BS * J * K, 256, 0, stream>>>(Z, sep, W, bias, out, ws, cnt);
}

// Round 11
// 57.449 us; speedup vs baseline: 1.3299x; 1.3299x over previous
//
#include <hip/hip_runtime.h>
#include <hip/hip_bf16.h>

#define BS  32
#define J   4
#define L   512
#define D   768
#define K   4
#define OUT 256
#define NUNITS (4 * BS * J * K)   // 2048 quarter-span units
// entity e = b*16 + j*4 + k (reference reshape order); sentence = e>>2 (128)

typedef float f4 __attribute__((ext_vector_type(4)));

// ---------------- Kernel A: dynamic quarter-span mean-pool ------------------
// 1024 persistent blocks x 256 threads (4 waves), all co-resident (4/CU).
// Units = (entity e, quarter q): tokens l = start + q + 4*m. Wave w takes
// m = w + 4*i (stride-16 rows). Blocks claim units via relaxed atomic counter
// until exhausted -> automatic load balance (no exact-fill tail). Each unit
// writes its 1/count-scaled partial row to ws[e][q][768].
__global__ __launch_bounds__(256) void pool_kernel(
    const float* __restrict__ Z,    // [BS,J,L,D]
    const int*   __restrict__ sep,  // [BS,J,K]
    float*       __restrict__ ws,   // [512][4][768] scaled quarter partials
    int*         __restrict__ ctr)  // claim counter (zeroed per call)
{
    __shared__ float part[4][D];    // 12 KB
    __shared__ int   s_unit;

    const int tid  = threadIdx.x;
    const int w    = tid >> 6;
    const int lane = tid & 63;

    for (;;) {
        if (tid == 0)
            s_unit = __hip_atomic_fetch_add(ctr, 1, __ATOMIC_RELAXED,
                                            __HIP_MEMORY_SCOPE_AGENT);
        __syncthreads();
        const int u = s_unit;                  // uniform across block
        if (u >= NUNITS) return;

        const int e    = u >> 2, q = u & 3;
        const int sent = e >> 2, k = e & 3;
        const int end   = sep[sent * K + k];
        const int prev  = (k == 0) ? 0 : sep[sent * K + k - 1];
        const int start = prev + 1;
        const float inv = 1.0f / (float)(end - start);
        const float* zbase = Z + (size_t)sent * L * D + lane * 4;

        f4 a0 = {0,0,0,0}, a1 = {0,0,0,0}, a2 = {0,0,0,0};
        for (int l = start + q + 4 * w; l < end; l += 16) {
            const float* r = zbase + (size_t)l * D;
            a0 += *(const f4*)(r);
            a1 += *(const f4*)(r + 256);
            a2 += *(const f4*)(r + 512);
        }

        *(f4*)&part[w][lane*4]       = a0;
        *(f4*)&part[w][lane*4 + 256] = a1;
        *(f4*)&part[w][lane*4 + 512] = a2;
        __syncthreads();

        if (tid < 192) {                       // 192 f4 = 768 floats
            f4 s = {0,0,0,0};
            #pragma unroll
            for (int ww = 0; ww < 4; ++ww) s += *(const f4*)&part[ww][tid*4];
            s *= inv;                          // pre-scale by 1/count
            *(f4*)&ws[((size_t)e * 4 + q) * D + tid*4] = s;
        }
        __syncthreads();                       // part[] + s_unit safe for reuse
    }
}

// ---------------- Kernel B: [512,768] @ [768,256] + bias (R5 proven) --------
// 512 blocks = (sentence g, col-quarter cq); 256 threads.
// Stage: p[e2][d] = sum_q ws[4g+e2][q][d] (quarters pre-scaled).
// Compute: wave w owns d-chunk of 192; lane=(dg,cl): d = w*192+dg+4i
// (conflict-free LDS broadcast), cl picks float4 of cols -> 16B coalesced
// W loads, 16 FMA/load. Cross-(wave,dg) LDS reduce, + bias, store.
__global__ __launch_bounds__(256) void gemm_kernel(
    const float* __restrict__ ws,   // [512][4][768]
    const float* __restrict__ W,    // [D, OUT]
    const float* __restrict__ bias, // [OUT]
    float*       __restrict__ out)  // [512, OUT]
{
    const int g  = blockIdx.x >> 2;
    const int cq = blockIdx.x & 3;

    __shared__ float p[K * D];                 // 12 KB
    __shared__ float red[16][K][64];           // 16 KB
    {
        const f4* a = (const f4*)(ws + (size_t)g * K * 4 * D); // 16 rows x 192 f4
        for (int i = threadIdx.x; i < K * 192; i += 256) {
            const int e2 = i / 192;            // magic-div
            const int t  = i - e2 * 192;
            const f4* base = a + (size_t)(e2 * 4) * 192;
            f4 v = base[t] + base[t + 192] + base[t + 2*192] + base[t + 3*192];
            *(f4*)&p[i * 4] = v;
        }
    }
    __syncthreads();

    const int w    = threadIdx.x >> 6;
    const int lane = threadIdx.x & 63;
    const int dg   = lane >> 4;
    const int cl   = lane & 15;
    const int colbase = cq * 64 + cl * 4;
    const int dbase   = w * 192 + dg;

    f4 acc0={0,0,0,0}, acc1={0,0,0,0}, acc2={0,0,0,0}, acc3={0,0,0,0};
    #pragma unroll 4
    for (int i = 0; i < 48; ++i) {
        const int d = dbase + 4 * i;
        f4 wv = *(const f4*)&W[(size_t)d * OUT + colbase];   // 16B coalesced
        acc0 += p[0 * D + d] * wv;             // LDS broadcast within dg group
        acc1 += p[1 * D + d] * wv;
        acc2 += p[2 * D + d] * wv;
        acc3 += p[3 * D + d] * wv;
    }

    const int r = w * 4 + dg;
    *(f4*)&red[r][0][cl * 4] = acc0;
    *(f4*)&red[r][1][cl * 4] = acc1;
    *(f4*)&red[r][2][cl * 4] = acc2;
    *(f4*)&red[r][3][cl * 4] = acc3;
    __syncthreads();

    const int e2  = threadIdx.x >> 6;          // entity
    const int col = threadIdx.x & 63;          // col within quarter
    float s = bias[cq * 64 + col];
    #pragma unroll
    for (int rr = 0; rr < 16; ++rr) s += red[rr][e2][col];  // conflict-free
    out[(size_t)(g * K + e2) * OUT + cq * 64 + col] = s;
}

extern "C" void kernel_launch(void* const* d_in, const int* in_sizes, int n_in,
                              void* d_out, int out_size, void* d_ws, size_t ws_size,
                              hipStream_t stream) {
    const float* Z    = (const float*)d_in[0];
    const int*   sep  = (const int*)d_in[1];
    const float* W    = (const float*)d_in[2];
    const float* bias = (const float*)d_in[3];
    float*       out  = (float*)d_out;
    float*       ws   = (float*)d_ws;                    // 6 MB quarter partials
    int*         ctr  = (int*)(ws + (size_t)512 * 4 * D);// +4 B claim counter

    hipMemsetAsync(ctr, 0, sizeof(int), stream);         // graph-legal node
    pool_kernel<<<2 * BS * J * K, 256, 0, stream>>>(Z, sep, ws, ctr);
    gemm_kernel<<<BS * J * K, 256, 0, stream>>>(ws, W, bias, out);
}

// Round 12
// 23.178 us; speedup vs baseline: 3.2963x; 2.4786x over previous
//
#include <hip/hip_runtime.h>
#include <hip/hip_bf16.h>

#define BS  32
#define J   4
#define L   512
#define D   768
#define K   4
#define OUT 256
// entity e = b*16 + j*4 + k (reference reshape order); sentence = e>>2 (128)

typedef float f4 __attribute__((ext_vector_type(4)));

// LDS row stride pad: 4 rows x 3456 floats x 4B = 55296 B (54 KB) per block.
// 160 KB/CU / 54 KB = 2 blocks/CU -> 512 resident slots for 1024 blocks:
// the hardware dispatcher backfills finished CUs = zero-overhead load balance.
#define PROW 3456

// ---------------- Kernel A: ragged span mean-pool (half-span blocks) --------
// 1024 blocks = entity e (512) x half h (2); 256 threads = 4 waves.
// Body identical to round-5 (proven best); only LDS footprint enlarged to cap
// residency at 2 blocks/CU.
__global__ __launch_bounds__(256) void pool_kernel(
    const float* __restrict__ Z,    // [BS,J,L,D]
    const int*   __restrict__ sep,  // [BS,J,K]
    float*       __restrict__ ws)   // [128][2][4][768] scaled partials
{
    __shared__ float part[4][PROW];            // 54 KB (12 KB used)

    const int blk  = blockIdx.x;     // 0..1023
    const int e    = blk >> 1, h = blk & 1;
    const int sent = e >> 2,  k = e & 3;
    const int end   = sep[sent * K + k];
    const int prev  = (k == 0) ? 0 : sep[sent * K + k - 1];
    const int start = prev + 1;
    const float inv = 1.0f / (float)(end - start);

    const int w    = threadIdx.x >> 6;
    const int lane = threadIdx.x & 63;
    const float* zbase = Z + (size_t)sent * L * D + lane * 4;

    f4 a0={0,0,0,0}, a1={0,0,0,0}, a2={0,0,0,0};
    f4 c0={0,0,0,0}, c1={0,0,0,0}, c2={0,0,0,0};

    int l = start + h + 2 * w;                 // this wave: stride 8
    for (; l + 8 < end; l += 16) {             // 2 tokens/iter: 6 loads in flight
        const float* r0 = zbase + (size_t)l * D;
        const float* r1 = zbase + (size_t)(l + 8) * D;
        a0 += *(const f4*)(r0);       a1 += *(const f4*)(r0 + 256);
        a2 += *(const f4*)(r0 + 512);
        c0 += *(const f4*)(r1);       c1 += *(const f4*)(r1 + 256);
        c2 += *(const f4*)(r1 + 512);
    }
    if (l < end) {
        const float* r0 = zbase + (size_t)l * D;
        a0 += *(const f4*)(r0);       a1 += *(const f4*)(r0 + 256);
        a2 += *(const f4*)(r0 + 512);
    }
    a0 += c0; a1 += c1; a2 += c2;

    *(f4*)&part[w][lane*4]       = a0;
    *(f4*)&part[w][lane*4 + 256] = a1;
    *(f4*)&part[w][lane*4 + 512] = a2;
    __syncthreads();

    const int t = threadIdx.x;
    if (t < 192) {                             // 192 f4 = 768 floats
        f4 s = {0,0,0,0};
        #pragma unroll
        for (int ww = 0; ww < 4; ++ww) s += *(const f4*)&part[ww][t*4];
        s *= inv;
        *(f4*)&ws[(((size_t)sent*2 + h)*K + k) * D + t*4] = s;  // pre-scaled
    }
}

// ---------------- Kernel B: [512,768] @ [768,256] + bias (R5 proven) --------
// 512 blocks = (sentence g, col-quarter cq); 256 threads.
// Stage: p[e][d] = ws[g][0][e][d] + ws[g][1][e][d]  (halves pre-scaled).
// Compute: wave w owns d-chunk of 192; lane=(dg,cl): d = w*192+dg+4i
// (conflict-free LDS broadcast), cl picks float4 of cols -> 16B coalesced
// W loads, 16 FMA/load. Cross-(wave,dg) LDS reduce, + bias, store.
__global__ __launch_bounds__(256) void gemm_kernel(
    const float* __restrict__ ws,   // [128][2][4][768]
    const float* __restrict__ W,    // [D, OUT]
    const float* __restrict__ bias, // [OUT]
    float*       __restrict__ out)  // [512, OUT]
{
    const int g  = blockIdx.x >> 2;
    const int cq = blockIdx.x & 3;

    __shared__ float p[K * D];                 // 12 KB
    __shared__ float red[16][K][64];           // 16 KB
    {
        const f4* a = (const f4*)(ws + (size_t)g * 2 * K * D);
        #pragma unroll
        for (int i = threadIdx.x; i < (K * D) / 4; i += 256) {
            f4 v = a[i] + a[i + (K * D) / 4];
            *(f4*)&p[i * 4] = v;
        }
    }
    __syncthreads();

    const int w    = threadIdx.x >> 6;
    const int lane = threadIdx.x & 63;
    const int dg   = lane >> 4;
    const int cl   = lane & 15;
    const int colbase = cq * 64 + cl * 4;
    const int dbase   = w * 192 + dg;

    f4 acc0={0,0,0,0}, acc1={0,0,0,0}, acc2={0,0,0,0}, acc3={0,0,0,0};
    #pragma unroll 4
    for (int i = 0; i < 48; ++i) {
        const int d = dbase + 4 * i;
        f4 wv = *(const f4*)&W[(size_t)d * OUT + colbase];   // 16B coalesced
        acc0 += p[0 * D + d] * wv;             // LDS broadcast within dg group
        acc1 += p[1 * D + d] * wv;
        acc2 += p[2 * D + d] * wv;
        acc3 += p[3 * D + d] * wv;
    }

    const int r = w * 4 + dg;
    *(f4*)&red[r][0][cl * 4] = acc0;
    *(f4*)&red[r][1][cl * 4] = acc1;
    *(f4*)&red[r][2][cl * 4] = acc2;
    *(f4*)&red[r][3][cl * 4] = acc3;
    __syncthreads();

    const int e2  = threadIdx.x >> 6;          // entity
    const int col = threadIdx.x & 63;          // col within quarter
    float s = bias[cq * 64 + col];
    #pragma unroll
    for (int rr = 0; rr < 16; ++rr) s += red[rr][e2][col];  // conflict-free
    out[(size_t)(g * K + e2) * OUT + cq * 64 + col] = s;
}

extern "C" void kernel_launch(void* const* d_in, const int* in_sizes, int n_in,
                              void* d_out, int out_size, void* d_ws, size_t ws_size,
                              hipStream_t stream) {
    const float* Z    = (const float*)d_in[0];
    const int*   sep  = (const int*)d_in[1];
    const float* W    = (const float*)d_in[2];
    const float* bias = (const float*)d_in[3];
    float*       out  = (float*)d_out;
    float*       ws   = (float*)d_ws;          // 128*2*4*768*4 = 3 MB scratch

    pool_kernel<<<2 * BS * J * K, 256, 0, stream>>>(Z, sep, ws);
    gemm_kernel<<<BS * J * K, 256, 0, stream>>>(ws, W, bias, out);
}